// Round 1
// baseline (696.351 us; speedup 1.0000x reference)
//
#include <hip/hip_runtime.h>
#include <hip/hip_bf16.h>
#include <stdint.h>

#define BB 32
#define TT 8192
#define II 256
#define SS 256
#define HH 256
#define NEGC 1e30f

typedef __bf16 bf16x8 __attribute__((ext_vector_type(8)));
typedef __bf16 bf16x4 __attribute__((ext_vector_type(4)));
typedef float f32x4 __attribute__((ext_vector_type(4)));

__device__ __forceinline__ float fast_tanh(float x) {
    float e = __expf(2.f * x);
    return 1.f - 2.f / (e + 1.f);
}

// ---------------------------------------------------------------------------
// Wi (= W1[:, S:]) -> bf16, row-major [H][I]
__global__ __launch_bounds__(256) void wi_cvt_kernel(const float* __restrict__ W1,
                                                     __bf16* __restrict__ wi) {
    int idx = blockIdx.x * 256 + threadIdx.x;  // 65536
    int h = idx >> 8, k = idx & 255;
    wi[idx] = (__bf16)W1[h * 512 + 256 + k];
}

// sws[b][h] = sum_s state[b][s] * W1[h][s]
__global__ __launch_bounds__(256) void sws_kernel(const float* __restrict__ state,
                                                  const float* __restrict__ W1,
                                                  float* __restrict__ sws) {
    int b = blockIdx.x, tid = threadIdx.x;
    __shared__ float sv[256];
    sv[tid] = state[b * 256 + tid];
    __syncthreads();
    const float* w1r = W1 + (size_t)tid * 512;
    float a = 0.f;
#pragma unroll 8
    for (int s = 0; s < 256; ++s) a += sv[s] * w1r[s];
    sws[b * 256 + tid] = a;
}

// ---------------------------------------------------------------------------
// att kernel: logit[row] = sum_h W2[h]*tanh( x[row,:]·Wi[h,:] + sws[b][h] ) - 1e30*(1-mask)
// MODE 0: read f32 x, also write x_bf16 cache.  MODE 1: read x_bf16.  MODE 2: read f32, no cache.
template <int MODE>
__global__ __launch_bounds__(256, 2) void att_kernel(
    const float* __restrict__ x, const __bf16* __restrict__ xbf_in,
    __bf16* __restrict__ xbf_out, const __bf16* __restrict__ wi,
    const float* __restrict__ w2, const float* __restrict__ sws,
    const float* __restrict__ mask, float* __restrict__ logit_out) {
    __shared__ char xs[64 * 512];        // 64 rows x 256 bf16, XOR-swizzled
    __shared__ float attp[4][64];

    const int tid = threadIdx.x;
    const int lane = tid & 63, w = tid >> 6;
    const size_t rowbase = (size_t)blockIdx.x * 64;
    const int b = (int)(rowbase >> 13);

    // ---- stage x tile into LDS (bf16, swizzled) ----
    if (MODE == 1) {
        const char* src = (const char*)xbf_in + rowbase * 512;
#pragma unroll
        for (int it = 0; it < 8; ++it) {
            int L = (it * 256 + tid) * 16;
            bf16x8 v = *(const bf16x8*)(src + L);
            int row = L >> 9, kb = L & 511;
            *(bf16x8*)(xs + row * 512 + (kb ^ ((row & 7) << 4))) = v;
        }
    } else {
        const float* src = x + rowbase * 256;
#pragma unroll
        for (int it = 0; it < 8; ++it) {
            int L = (it * 256 + tid) * 16;   // byte offset within bf16 tile
            int e = L >> 1;                  // f32 element offset (8 floats)
            float4 f0 = *(const float4*)(src + e);
            float4 f1 = *(const float4*)(src + e + 4);
            bf16x8 v;
            v[0] = (__bf16)f0.x; v[1] = (__bf16)f0.y; v[2] = (__bf16)f0.z; v[3] = (__bf16)f0.w;
            v[4] = (__bf16)f1.x; v[5] = (__bf16)f1.y; v[6] = (__bf16)f1.z; v[7] = (__bf16)f1.w;
            int row = L >> 9, kb = L & 511;
            *(bf16x8*)(xs + row * 512 + (kb ^ ((row & 7) << 4))) = v;
            if (MODE == 0)
                *(bf16x8*)((char*)xbf_out + rowbase * 512 + L) = v;
        }
    }
    __syncthreads();

    // ---- MFMA: acc[fm][fn] = x_tile(64xK) · Wi^T slice (wave w covers cols w*64..+64) ----
    const int l15 = lane & 15, lg = lane >> 4;
    f32x4 acc[4][4] = {};
    const char* wib = (const char*)wi + (size_t)(w * 64 + l15) * 512 + lg * 16;
#pragma unroll
    for (int kk = 0; kk < 8; ++kk) {
        bf16x8 bfrag[4];
#pragma unroll
        for (int fn = 0; fn < 4; ++fn)
            bfrag[fn] = *(const bf16x8*)(wib + fn * 16 * 512 + kk * 64);
        bf16x8 afrag[4];
#pragma unroll
        for (int fm = 0; fm < 4; ++fm) {
            int row = fm * 16 + l15;
            int kb = kk * 64 + lg * 16;
            afrag[fm] = *(const bf16x8*)(xs + row * 512 + (kb ^ ((row & 7) << 4)));
        }
#pragma unroll
        for (int fm = 0; fm < 4; ++fm)
#pragma unroll
            for (int fn = 0; fn < 4; ++fn)
                acc[fm][fn] = __builtin_amdgcn_mfma_f32_16x16x32_bf16(
                    afrag[fm], bfrag[fn], acc[fm][fn], 0, 0, 0);
    }

    // ---- epilogue: att = sum_h W2[h] * tanh(acc + sws[b][h]) ----
    float w2v[4], swsv[4];
#pragma unroll
    for (int fn = 0; fn < 4; ++fn) {
        int h = w * 64 + fn * 16 + l15;
        w2v[fn] = w2[h];
        swsv[fn] = sws[b * 256 + h];
    }
#pragma unroll
    for (int fm = 0; fm < 4; ++fm) {
        float part[4];
#pragma unroll
        for (int r = 0; r < 4; ++r) {
            float s = 0.f;
#pragma unroll
            for (int fn = 0; fn < 4; ++fn) {
                float hv = acc[fm][fn][r] + swsv[fn];
                s += w2v[fn] * fast_tanh(hv);
            }
            part[r] = s;
        }
#pragma unroll
        for (int m = 1; m < 16; m <<= 1)
#pragma unroll
            for (int r = 0; r < 4; ++r) part[r] += __shfl_xor(part[r], m, 64);
        if (l15 == 0) {
#pragma unroll
            for (int r = 0; r < 4; ++r) attp[w][fm * 16 + lg * 4 + r] = part[r];
        }
    }
    __syncthreads();
    if (tid < 64) {
        float att = attp[0][tid] + attp[1][tid] + attp[2][tid] + attp[3][tid];
        float mv = mask[rowbase + tid];
        logit_out[rowbase + tid] = att - NEGC * (1.f - mv);
    }
}

// ---------------------------------------------------------------------------
__global__ __launch_bounds__(256) void softmax_kernel(const float* __restrict__ logit,
                                                      float* __restrict__ p) {
    __shared__ float lbuf[TT];
    __shared__ float red[4], red2[4];
    int b = blockIdx.x, tid = threadIdx.x;
    const float* lp = logit + (size_t)b * TT;
    float m = -3.4e38f;
    for (int t = tid; t < TT; t += 256) {
        float v = lp[t];
        lbuf[t] = v;
        m = fmaxf(m, v);
    }
#pragma unroll
    for (int o = 1; o < 64; o <<= 1) m = fmaxf(m, __shfl_xor(m, o, 64));
    if ((tid & 63) == 0) red[tid >> 6] = m;
    __syncthreads();
    m = fmaxf(fmaxf(red[0], red[1]), fmaxf(red[2], red[3]));
    float s = 0.f;
    for (int t = tid; t < TT; t += 256) s += __expf(lbuf[t] - m);
#pragma unroll
    for (int o = 1; o < 64; o <<= 1) s += __shfl_xor(s, o, 64);
    if ((tid & 63) == 0) red2[tid >> 6] = s;
    __syncthreads();
    s = red2[0] + red2[1] + red2[2] + red2[3];
    float inv = 1.f / s;
    float* pp = p + (size_t)b * TT;
    for (int t = tid; t < TT; t += 256) pp[t] = __expf(lbuf[t] - m) * inv;
}

// ---------------------------------------------------------------------------
// out_part[b][c][i] = sum_{t in chunk c} p[b,t] * x[b,t,i]   (8 chunks of 1024)
template <int MODE>  // 0: bf16 x cache, 2: f32 x
__global__ __launch_bounds__(256) void outpart_kernel(const float* __restrict__ p,
                                                      const float* __restrict__ xf,
                                                      const __bf16* __restrict__ xbf,
                                                      float* __restrict__ out_part) {
    int b = blockIdx.x >> 3, c = blockIdx.x & 7;
    int tid = threadIdx.x;
    int ig = tid & 63, tg = tid >> 6;
    __shared__ float pl[1024];
    __shared__ float sacc[4][256];
    const size_t tbase = (size_t)b * TT + (size_t)c * 1024;
    for (int t = tid; t < 1024; t += 256) pl[t] = p[tbase + t];
    __syncthreads();
    float a0 = 0, a1 = 0, a2 = 0, a3 = 0;
    if (MODE == 0) {
        const __bf16* xp = xbf + tbase * 256 + ig * 4;
        for (int t = tg; t < 1024; t += 4) {
            float pv = pl[t];
            bf16x4 v = *(const bf16x4*)(xp + (size_t)t * 256);
            a0 += pv * (float)v[0];
            a1 += pv * (float)v[1];
            a2 += pv * (float)v[2];
            a3 += pv * (float)v[3];
        }
    } else {
        const float* xp = xf + tbase * 256 + ig * 4;
        for (int t = tg; t < 1024; t += 4) {
            float pv = pl[t];
            float4 v = *(const float4*)(xp + (size_t)t * 256);
            a0 += pv * v.x;
            a1 += pv * v.y;
            a2 += pv * v.z;
            a3 += pv * v.w;
        }
    }
    sacc[tg][ig * 4 + 0] = a0;
    sacc[tg][ig * 4 + 1] = a1;
    sacc[tg][ig * 4 + 2] = a2;
    sacc[tg][ig * 4 + 3] = a3;
    __syncthreads();
    if (tid < 256) {
        float s = sacc[0][tid] + sacc[1][tid] + sacc[2][tid] + sacc[3][tid];
        out_part[(size_t)(b * 8 + c) * 256 + tid] = s;
    }
}

// ---------------------------------------------------------------------------
// GRU cell + sws2[b][h] = sum_s state[b][s]*W1[h][s]
__global__ __launch_bounds__(256) void gru_sws_kernel(
    const float* __restrict__ out_part, const float* __restrict__ init,
    const float* __restrict__ w_ih, const float* __restrict__ w_hh,
    const float* __restrict__ b_ih, const float* __restrict__ b_hh,
    const float* __restrict__ W1, float* __restrict__ sws2) {
    int b = blockIdx.x, tid = threadIdx.x;
    __shared__ float outv[256], initv[256], statev[256];
    __shared__ float gi[768], gh[768];
    float o = 0.f;
#pragma unroll
    for (int c = 0; c < 8; ++c) o += out_part[(size_t)(b * 8 + c) * 256 + tid];
    outv[tid] = o;
    initv[tid] = init[b * 256 + tid];
    __syncthreads();
#pragma unroll
    for (int kb = 0; kb < 3; ++kb) {
        int k = kb * 256 + tid;
        const float* wir = w_ih + (size_t)k * 256;
        const float* whr = w_hh + (size_t)k * 256;
        float gia = b_ih[k], gha = b_hh[k];
#pragma unroll 8
        for (int i = 0; i < 256; ++i) {
            gia += outv[i] * wir[i];
            gha += initv[i] * whr[i];
        }
        gi[k] = gia;
        gh[k] = gha;
    }
    __syncthreads();
    {
        float r = 1.f / (1.f + __expf(-(gi[tid] + gh[tid])));
        float z = 1.f / (1.f + __expf(-(gi[256 + tid] + gh[256 + tid])));
        float n = fast_tanh(gi[512 + tid] + r * gh[512 + tid]);
        statev[tid] = (1.f - z) * n + z * initv[tid];
    }
    __syncthreads();
    {
        const float* w1r = W1 + (size_t)tid * 512;
        float a = 0.f;
#pragma unroll 8
        for (int s = 0; s < 256; ++s) a += statev[s] * w1r[s];
        sws2[b * 256 + tid] = a;
    }
}

// ---------------------------------------------------------------------------
extern "C" void kernel_launch(void* const* d_in, const int* in_sizes, int n_in,
                              void* d_out, int out_size, void* d_ws, size_t ws_size,
                              hipStream_t stream) {
    const float* x = (const float*)d_in[0];
    const float* init = (const float*)d_in[1];
    const float* mask = (const float*)d_in[2];
    const float* W1 = (const float*)d_in[3];
    const float* W2 = (const float*)d_in[4];
    const float* w_ih = (const float*)d_in[5];
    const float* w_hh = (const float*)d_in[6];
    const float* b_ih = (const float*)d_in[7];
    const float* b_hh = (const float*)d_in[8];
    float* out = (float*)d_out;

    char* ws = (char*)d_ws;
    size_t off = 0;
    auto alloc = [&](size_t sz) {
        char* p = ws + off;
        off += (sz + 255) & ~(size_t)255;
        return p;
    };
    float* p_buf = (float*)alloc((size_t)BB * TT * 4);
    __bf16* wi = (__bf16*)alloc((size_t)HH * II * 2);
    float* sws1 = (float*)alloc(BB * 256 * 4);
    float* sws2 = (float*)alloc(BB * 256 * 4);
    float* out_part = (float*)alloc(BB * 8 * 256 * 4);
    size_t small_off = off;
    __bf16* xbf = (__bf16*)alloc((size_t)BB * TT * II * 2);
    const bool big = (off <= ws_size);
    (void)small_off;
    (void)in_sizes; (void)n_in; (void)out_size;

    wi_cvt_kernel<<<256, 256, 0, stream>>>(W1, wi);
    sws_kernel<<<32, 256, 0, stream>>>(init, W1, sws1);

    const int ntiles = BB * TT / 64;  // 4096
    if (big)
        att_kernel<0><<<ntiles, 256, 0, stream>>>(x, nullptr, xbf, wi, W2, sws1, mask, out);
    else
        att_kernel<2><<<ntiles, 256, 0, stream>>>(x, nullptr, nullptr, wi, W2, sws1, mask, out);

    softmax_kernel<<<32, 256, 0, stream>>>(out, p_buf);

    if (big)
        outpart_kernel<0><<<256, 256, 0, stream>>>(p_buf, nullptr, xbf, out_part);
    else
        outpart_kernel<2><<<256, 256, 0, stream>>>(p_buf, x, nullptr, out_part);

    gru_sws_kernel<<<32, 256, 0, stream>>>(out_part, init, w_ih, w_hh, b_ih, b_hh, W1, sws2);

    if (big)
        att_kernel<1><<<ntiles, 256, 0, stream>>>(nullptr, xbf, nullptr, wi, W2, sws2, mask,
                                                  out + (size_t)BB * TT);
    else
        att_kernel<2><<<ntiles, 256, 0, stream>>>(x, nullptr, nullptr, wi, W2, sws2, mask,
                                                  out + (size_t)BB * TT);
}

// Round 2
// 649.132 us; speedup vs baseline: 1.0727x; 1.0727x over previous
//
#include <hip/hip_runtime.h>
#include <hip/hip_bf16.h>
#include <stdint.h>

#define BB 32
#define TT 8192
#define II 256
#define SS 256
#define HH 256
#define NEGC 1e30f

typedef __bf16 bf16x8 __attribute__((ext_vector_type(8)));
typedef __bf16 bf16x4 __attribute__((ext_vector_type(4)));
typedef float f32x4 __attribute__((ext_vector_type(4)));

__device__ __forceinline__ float fast_tanh(float x) {
    float e = __expf(2.f * x);
    return 1.f - 2.f * __builtin_amdgcn_rcpf(e + 1.f);
}
__device__ __forceinline__ float fast_sigmoid(float x) {
    return __builtin_amdgcn_rcpf(1.f + __expf(-x));
}

// ---------------------------------------------------------------------------
// Wi (= W1[:, S:]) -> bf16, row-major [H][I]
__global__ __launch_bounds__(256) void wi_cvt_kernel(const float* __restrict__ W1,
                                                     __bf16* __restrict__ wi) {
    int idx = blockIdx.x * 256 + threadIdx.x;  // 65536
    int h = idx >> 8, k = idx & 255;
    wi[idx] = (__bf16)W1[h * 512 + 256 + k];
}

// ---------------------------------------------------------------------------
// sws[b][h] = sum_s state[b][s] * W1[h][s]  — 16 blocks, block j handles h rows
// [j*16, j*16+16) for ALL 32 batches. Weight rows read by exactly one block.
__global__ __launch_bounds__(256) void sws_slice_kernel(const float* __restrict__ state,
                                                        const float* __restrict__ W1,
                                                        float* __restrict__ sws) {
    __shared__ float sv[32 * 257];
    int tid = threadIdx.x;
    for (int e = tid; e < 8192; e += 256) {
        int b = e >> 8, s = e & 255;
        sv[b * 257 + s] = state[b * 256 + s];
    }
    __syncthreads();
    int hl = tid >> 4, bg = tid & 15;  // 16 h-rows, 2 batches per thread
    int h = blockIdx.x * 16 + hl;
    const float* w1r = W1 + (size_t)h * 512;
    float a0 = 0.f, a1 = 0.f;
#pragma unroll 4
    for (int s = 0; s < 256; ++s) {
        float w = w1r[s];
        a0 += w * sv[(bg * 2 + 0) * 257 + s];
        a1 += w * sv[(bg * 2 + 1) * 257 + s];
    }
    sws[(bg * 2 + 0) * 256 + h] = a0;
    sws[(bg * 2 + 1) * 256 + h] = a1;
}

// ---------------------------------------------------------------------------
// att kernel: logit[row] = sum_h W2[h]*tanh( x[row,:]·Wi[h,:] + sws[b][h] ) - 1e30*(1-mask)
// MODE 0: read f32 x, also write x_bf16 cache.  MODE 1: read x_bf16.  MODE 2: f32, no cache.
template <int MODE>
__global__ __launch_bounds__(256, 3) void att_kernel(
    const float* __restrict__ x, const __bf16* __restrict__ xbf_in,
    __bf16* __restrict__ xbf_out, const __bf16* __restrict__ wi,
    const float* __restrict__ w2, const float* __restrict__ sws,
    const float* __restrict__ mask, float* __restrict__ logit_out) {
    __shared__ char xs[64 * 512];        // 64 rows x 256 bf16, XOR-swizzled
    __shared__ float attp[4][64];

    const int tid = threadIdx.x;
    const int lane = tid & 63, w = tid >> 6;
    const size_t rowbase = (size_t)blockIdx.x * 64;
    const int b = (int)(rowbase >> 13);

    // ---- stage x tile into LDS (bf16, swizzled) ----
    if (MODE == 1) {
        const char* src = (const char*)xbf_in + rowbase * 512;
#pragma unroll
        for (int it = 0; it < 8; ++it) {
            int L = (it * 256 + tid) * 16;
            bf16x8 v = *(const bf16x8*)(src + L);
            int row = L >> 9, kb = L & 511;
            *(bf16x8*)(xs + row * 512 + (kb ^ ((row & 7) << 4))) = v;
        }
    } else {
        const float* src = x + rowbase * 256;
#pragma unroll
        for (int it = 0; it < 8; ++it) {
            int L = (it * 256 + tid) * 16;   // byte offset within bf16 tile
            int e = L >> 1;                  // f32 element offset (8 floats)
            float4 f0 = *(const float4*)(src + e);
            float4 f1 = *(const float4*)(src + e + 4);
            bf16x8 v;
            v[0] = (__bf16)f0.x; v[1] = (__bf16)f0.y; v[2] = (__bf16)f0.z; v[3] = (__bf16)f0.w;
            v[4] = (__bf16)f1.x; v[5] = (__bf16)f1.y; v[6] = (__bf16)f1.z; v[7] = (__bf16)f1.w;
            int row = L >> 9, kb = L & 511;
            *(bf16x8*)(xs + row * 512 + (kb ^ ((row & 7) << 4))) = v;
            if (MODE == 0)
                *(bf16x8*)((char*)xbf_out + rowbase * 512 + L) = v;
        }
    }
    __syncthreads();

    // ---- MFMA: acc[fm][fn] = x_tile(64xK) · Wi^T slice (wave w covers cols w*64..+64) ----
    const int l15 = lane & 15, lg = lane >> 4;
    f32x4 acc[4][4] = {};
    const char* wib = (const char*)wi + (size_t)(w * 64 + l15) * 512 + lg * 16;
#pragma unroll
    for (int kk = 0; kk < 8; ++kk) {
        bf16x8 bfrag[4];
#pragma unroll
        for (int fn = 0; fn < 4; ++fn)
            bfrag[fn] = *(const bf16x8*)(wib + fn * 16 * 512 + kk * 64);
        bf16x8 afrag[4];
#pragma unroll
        for (int fm = 0; fm < 4; ++fm) {
            int row = fm * 16 + l15;
            int kb = kk * 64 + lg * 16;
            afrag[fm] = *(const bf16x8*)(xs + row * 512 + (kb ^ ((row & 7) << 4)));
        }
#pragma unroll
        for (int fm = 0; fm < 4; ++fm)
#pragma unroll
            for (int fn = 0; fn < 4; ++fn)
                acc[fm][fn] = __builtin_amdgcn_mfma_f32_16x16x32_bf16(
                    afrag[fm], bfrag[fn], acc[fm][fn], 0, 0, 0);
    }

    // ---- epilogue: att = sum_h W2[h] * tanh(acc + sws[b][h]) ----
    float w2v[4], swsv[4];
#pragma unroll
    for (int fn = 0; fn < 4; ++fn) {
        int h = w * 64 + fn * 16 + l15;
        w2v[fn] = w2[h];
        swsv[fn] = sws[b * 256 + h];
    }
    const bool hi8 = (l15 & 8) != 0, hi4 = (l15 & 4) != 0;
    const int ridx = ((l15 & 8) >> 2) | ((l15 & 4) >> 2);
#pragma unroll
    for (int fm = 0; fm < 4; ++fm) {
        float part[4];
#pragma unroll
        for (int r = 0; r < 4; ++r) {
            float s = 0.f;
#pragma unroll
            for (int fn = 0; fn < 4; ++fn) {
                float hv = acc[fm][fn][r] + swsv[fn];
                s += w2v[fn] * fast_tanh(hv);
            }
            part[r] = s;
        }
        // distributed butterfly reduce over the 16 l15 lanes:
        // round 1 (xor 8): low half keeps {r0,r1}, high half keeps {r2,r3}
        float s0 = hi8 ? part[0] : part[2];
        float s1 = hi8 ? part[1] : part[3];
        float r0 = __shfl_xor(s0, 8, 64);
        float r1 = __shfl_xor(s1, 8, 64);
        float a0 = (hi8 ? part[2] : part[0]) + r0;
        float a1 = (hi8 ? part[3] : part[1]) + r1;
        // round 2 (xor 4): keep one of {a0,a1}
        float s2 = hi4 ? a0 : a1;
        float r2 = __shfl_xor(s2, 4, 64);
        float bsum = (hi4 ? a1 : a0) + r2;
        // rounds 3,4: finish sum across remaining lane bits
        bsum += __shfl_xor(bsum, 2, 64);
        bsum += __shfl_xor(bsum, 1, 64);
        if ((l15 & 3) == 0) attp[w][fm * 16 + lg * 4 + ridx] = bsum;
    }
    __syncthreads();
    if (tid < 64) {
        float att = attp[0][tid] + attp[1][tid] + attp[2][tid] + attp[3][tid];
        float mv = mask[rowbase + tid];
        logit_out[rowbase + tid] = att - NEGC * (1.f - mv);
    }
}

// ---------------------------------------------------------------------------
// per-chunk softmax stats: stat[bc] = {max, sum exp(l - max)} over 1024 logits
__global__ __launch_bounds__(256) void chunkstat_kernel(const float* __restrict__ logit,
                                                        float2* __restrict__ stat) {
    __shared__ float redm[4], reds[4];
    int bc = blockIdx.x, tid = threadIdx.x;
    const float* lp = logit + (size_t)bc * 1024;
    float4 v = *(const float4*)(lp + tid * 4);
    float m = fmaxf(fmaxf(v.x, v.y), fmaxf(v.z, v.w));
#pragma unroll
    for (int o = 1; o < 64; o <<= 1) m = fmaxf(m, __shfl_xor(m, o, 64));
    if ((tid & 63) == 0) redm[tid >> 6] = m;
    __syncthreads();
    m = fmaxf(fmaxf(redm[0], redm[1]), fmaxf(redm[2], redm[3]));
    float s = __expf(v.x - m) + __expf(v.y - m) + __expf(v.z - m) + __expf(v.w - m);
#pragma unroll
    for (int o = 1; o < 64; o <<= 1) s += __shfl_xor(s, o, 64);
    if ((tid & 63) == 0) reds[tid >> 6] = s;
    __syncthreads();
    if (tid == 0) {
        float2 st;
        st.x = m;
        st.y = reds[0] + reds[1] + reds[2] + reds[3];
        stat[bc] = st;
    }
}

// ---------------------------------------------------------------------------
// out_part[b][c][i] = sum_{t in chunk c} p[b,t]*x[b,t,i], p computed online from
// logits + chunk stats. 256 blocks (b,c), chunks of 1024.
template <int MODE>  // 0: bf16 x cache, 2: f32 x
__global__ __launch_bounds__(256) void outpart_kernel(
    const float* __restrict__ logit, const float2* __restrict__ stat,
    const float* __restrict__ xf, const __bf16* __restrict__ xbf,
    float* __restrict__ out_part) {
    int b = blockIdx.x >> 3, c = blockIdx.x & 7;
    int tid = threadIdx.x;
    int ig = tid & 63, tg = tid >> 6;
    __shared__ float pl[1024];
    __shared__ float sacc[4][256];
    // global softmax normalizers for batch b (redundant per-thread, broadcast loads)
    float m = -3.4e38f;
#pragma unroll
    for (int cc = 0; cc < 8; ++cc) m = fmaxf(m, stat[b * 8 + cc].x);
    float ssum = 0.f;
#pragma unroll
    for (int cc = 0; cc < 8; ++cc) {
        float2 st = stat[b * 8 + cc];
        ssum += st.y * __expf(st.x - m);
    }
    float invs = 1.f / ssum;
    const size_t tbase = (size_t)b * TT + (size_t)c * 1024;
    for (int t = tid; t < 1024; t += 256)
        pl[t] = __expf(logit[tbase + t] - m) * invs;
    __syncthreads();
    float a0 = 0, a1 = 0, a2 = 0, a3 = 0;
    if (MODE == 0) {
        const __bf16* xp = xbf + tbase * 256 + ig * 4;
        for (int t = tg; t < 1024; t += 4) {
            float pv = pl[t];
            bf16x4 v = *(const bf16x4*)(xp + (size_t)t * 256);
            a0 += pv * (float)v[0];
            a1 += pv * (float)v[1];
            a2 += pv * (float)v[2];
            a3 += pv * (float)v[3];
        }
    } else {
        const float* xp = xf + tbase * 256 + ig * 4;
        for (int t = tg; t < 1024; t += 4) {
            float pv = pl[t];
            float4 v = *(const float4*)(xp + (size_t)t * 256);
            a0 += pv * v.x;
            a1 += pv * v.y;
            a2 += pv * v.z;
            a3 += pv * v.w;
        }
    }
    sacc[tg][ig * 4 + 0] = a0;
    sacc[tg][ig * 4 + 1] = a1;
    sacc[tg][ig * 4 + 2] = a2;
    sacc[tg][ig * 4 + 3] = a3;
    __syncthreads();
    if (tid < 256) {
        float s = sacc[0][tid] + sacc[1][tid] + sacc[2][tid] + sacc[3][tid];
        out_part[(size_t)(b * 8 + c) * 256 + tid] = s;
    }
}

// ---------------------------------------------------------------------------
// GRU gemm: gi[k][b] = b_ih[k] + sum_i w_ih[k][i]*out[b][i]; gh analog.
// 48 blocks; block j handles k rows [j*16, j*16+16) for all 32 batches.
__global__ __launch_bounds__(256) void gru_gemm_kernel(
    const float* __restrict__ out_part, const float* __restrict__ init,
    const float* __restrict__ w_ih, const float* __restrict__ w_hh,
    const float* __restrict__ b_ih, const float* __restrict__ b_hh,
    float* __restrict__ gi, float* __restrict__ gh) {
    __shared__ float outv[32 * 257];
    __shared__ float initv[32 * 257];
    int tid = threadIdx.x;
    for (int e = tid; e < 8192; e += 256) {
        int b = e >> 8, i = e & 255;
        float o = 0.f;
#pragma unroll
        for (int c = 0; c < 8; ++c) o += out_part[(size_t)(b * 8 + c) * 256 + i];
        outv[b * 257 + i] = o;
        initv[b * 257 + i] = init[b * 256 + i];
    }
    __syncthreads();
    int kl = tid >> 4, bg = tid & 15;  // 16 k-rows, 2 batches per thread
    int k = blockIdx.x * 16 + kl;
    const float* wir = w_ih + (size_t)k * 256;
    const float* whr = w_hh + (size_t)k * 256;
    float gia0 = b_ih[k], gia1 = gia0;
    float gha0 = b_hh[k], gha1 = gha0;
#pragma unroll 4
    for (int i = 0; i < 256; ++i) {
        float wiv = wir[i], whv = whr[i];
        gia0 += wiv * outv[(bg * 2 + 0) * 257 + i];
        gia1 += wiv * outv[(bg * 2 + 1) * 257 + i];
        gha0 += whv * initv[(bg * 2 + 0) * 257 + i];
        gha1 += whv * initv[(bg * 2 + 1) * 257 + i];
    }
    gi[k * 32 + bg * 2 + 0] = gia0;
    gi[k * 32 + bg * 2 + 1] = gia1;
    gh[k * 32 + bg * 2 + 0] = gha0;
    gh[k * 32 + bg * 2 + 1] = gha1;
}

// GRU pointwise: state[b][s]
__global__ __launch_bounds__(256) void gru_point_kernel(
    const float* __restrict__ gi, const float* __restrict__ gh,
    const float* __restrict__ init, float* __restrict__ state) {
    int b = blockIdx.x, s = threadIdx.x;
    float gir = gi[s * 32 + b], giz = gi[(256 + s) * 32 + b], gin = gi[(512 + s) * 32 + b];
    float ghr = gh[s * 32 + b], ghz = gh[(256 + s) * 32 + b], ghn = gh[(512 + s) * 32 + b];
    float r = fast_sigmoid(gir + ghr);
    float z = fast_sigmoid(giz + ghz);
    float n = fast_tanh(gin + r * ghn);
    float h0 = init[b * 256 + s];
    state[b * 256 + s] = (1.f - z) * n + z * h0;
}

// ---------------------------------------------------------------------------
extern "C" void kernel_launch(void* const* d_in, const int* in_sizes, int n_in,
                              void* d_out, int out_size, void* d_ws, size_t ws_size,
                              hipStream_t stream) {
    const float* x = (const float*)d_in[0];
    const float* init = (const float*)d_in[1];
    const float* mask = (const float*)d_in[2];
    const float* W1 = (const float*)d_in[3];
    const float* W2 = (const float*)d_in[4];
    const float* w_ih = (const float*)d_in[5];
    const float* w_hh = (const float*)d_in[6];
    const float* b_ih = (const float*)d_in[7];
    const float* b_hh = (const float*)d_in[8];
    float* out = (float*)d_out;

    char* ws = (char*)d_ws;
    size_t off = 0;
    auto alloc = [&](size_t sz) {
        char* p = ws + off;
        off += (sz + 255) & ~(size_t)255;
        return p;
    };
    __bf16* wi = (__bf16*)alloc((size_t)HH * II * 2);
    float* sws1 = (float*)alloc(BB * 256 * 4);
    float* sws2 = (float*)alloc(BB * 256 * 4);
    float* out_part = (float*)alloc(BB * 8 * 256 * 4);
    float2* stat = (float2*)alloc(BB * 8 * 8);
    float* gi_buf = (float*)alloc(768 * 32 * 4);
    float* gh_buf = (float*)alloc(768 * 32 * 4);
    float* state_buf = (float*)alloc(BB * 256 * 4);
    __bf16* xbf = (__bf16*)alloc((size_t)BB * TT * II * 2);
    const bool big = (off <= ws_size);
    (void)in_sizes; (void)n_in; (void)out_size;

    wi_cvt_kernel<<<256, 256, 0, stream>>>(W1, wi);
    sws_slice_kernel<<<16, 256, 0, stream>>>(init, W1, sws1);

    const int ntiles = BB * TT / 64;  // 4096
    if (big)
        att_kernel<0><<<ntiles, 256, 0, stream>>>(x, nullptr, xbf, wi, W2, sws1, mask, out);
    else
        att_kernel<2><<<ntiles, 256, 0, stream>>>(x, nullptr, nullptr, wi, W2, sws1, mask, out);

    chunkstat_kernel<<<256, 256, 0, stream>>>(out, stat);

    if (big)
        outpart_kernel<0><<<256, 256, 0, stream>>>(out, stat, nullptr, xbf, out_part);
    else
        outpart_kernel<2><<<256, 256, 0, stream>>>(out, stat, x, nullptr, out_part);

    gru_gemm_kernel<<<48, 256, 0, stream>>>(out_part, init, w_ih, w_hh, b_ih, b_hh,
                                            gi_buf, gh_buf);
    gru_point_kernel<<<32, 256, 0, stream>>>(gi_buf, gh_buf, init, state_buf);
    sws_slice_kernel<<<16, 256, 0, stream>>>(state_buf, W1, sws2);

    if (big)
        att_kernel<1><<<ntiles, 256, 0, stream>>>(nullptr, xbf, nullptr, wi, W2, sws2, mask,
                                                  out + (size_t)BB * TT);
    else
        att_kernel<2><<<ntiles, 256, 0, stream>>>(x, nullptr, nullptr, wi, W2, sws2, mask,
                                                  out + (size_t)BB * TT);
}

// Round 3
// 565.013 us; speedup vs baseline: 1.2325x; 1.1489x over previous
//
#include <hip/hip_runtime.h>
#include <hip/hip_bf16.h>
#include <stdint.h>

#define BB 32
#define TT 8192
#define II 256
#define SS 256
#define HH 256
#define NEGC 1e30f

typedef __bf16 bf16x8 __attribute__((ext_vector_type(8)));
typedef __bf16 bf16x4 __attribute__((ext_vector_type(4)));
typedef float f32x4 __attribute__((ext_vector_type(4)));

__device__ __forceinline__ float fast_tanh(float x) {
    float e = __expf(2.f * x);
    return 1.f - 2.f * __builtin_amdgcn_rcpf(e + 1.f);
}
__device__ __forceinline__ float fast_sigmoid(float x) {
    return __builtin_amdgcn_rcpf(1.f + __expf(-x));
}

// ---------------------------------------------------------------------------
// Fused prep: blocks 0..255 convert Wi (= W1[:, S:]) to bf16 [H][I];
// blocks 256..271 compute sws1[b][h] = sum_s init[b][s]*W1[h][s].
__global__ __launch_bounds__(256) void prep_kernel(const float* __restrict__ W1,
                                                   const float* __restrict__ init,
                                                   __bf16* __restrict__ wi,
                                                   float* __restrict__ sws) {
    __shared__ float sv[32 * 257];
    int tid = threadIdx.x;
    if (blockIdx.x < 256) {
        int idx = blockIdx.x * 256 + tid;
        int h = idx >> 8, k = idx & 255;
        wi[idx] = (__bf16)W1[h * 512 + 256 + k];
        return;
    }
    for (int e = tid; e < 8192; e += 256) {
        int b = e >> 8, s = e & 255;
        sv[b * 257 + s] = init[b * 256 + s];
    }
    __syncthreads();
    int hl = tid >> 4, bg = tid & 15;
    int h = (blockIdx.x - 256) * 16 + hl;
    const float* w1r = W1 + (size_t)h * 512;
    float a0 = 0.f, a1 = 0.f;
#pragma unroll 4
    for (int s = 0; s < 256; ++s) {
        float w = w1r[s];
        a0 += w * sv[(bg * 2 + 0) * 257 + s];
        a1 += w * sv[(bg * 2 + 1) * 257 + s];
    }
    sws[(bg * 2 + 0) * 256 + h] = a0;
    sws[(bg * 2 + 1) * 256 + h] = a1;
}

// ---------------------------------------------------------------------------
// sws[b][h] = sum_s state[b][s] * W1[h][s]  — 16 blocks
__global__ __launch_bounds__(256) void sws_slice_kernel(const float* __restrict__ state,
                                                        const float* __restrict__ W1,
                                                        float* __restrict__ sws) {
    __shared__ float sv[32 * 257];
    int tid = threadIdx.x;
    for (int e = tid; e < 8192; e += 256) {
        int b = e >> 8, s = e & 255;
        sv[b * 257 + s] = state[b * 256 + s];
    }
    __syncthreads();
    int hl = tid >> 4, bg = tid & 15;
    int h = blockIdx.x * 16 + hl;
    const float* w1r = W1 + (size_t)h * 512;
    float a0 = 0.f, a1 = 0.f;
#pragma unroll 4
    for (int s = 0; s < 256; ++s) {
        float w = w1r[s];
        a0 += w * sv[(bg * 2 + 0) * 257 + s];
        a1 += w * sv[(bg * 2 + 1) * 257 + s];
    }
    sws[(bg * 2 + 0) * 256 + h] = a0;
    sws[(bg * 2 + 1) * 256 + h] = a1;
}

// ---------------------------------------------------------------------------
// att kernel: logit[row] = sum_h W2[h]*tanh( x[row,:]·Wi[h,:] + sws[b][h] ) - 1e30*(1-mask)
// MODE 0: read f32 x, also write x_bf16 cache.  MODE 1: read x_bf16.  MODE 2: f32, no cache.
template <int MODE>
__global__ __launch_bounds__(256, 3) void att_kernel(
    const float* __restrict__ x, const __bf16* __restrict__ xbf_in,
    __bf16* __restrict__ xbf_out, const __bf16* __restrict__ wi,
    const float* __restrict__ w2, const float* __restrict__ sws,
    const float* __restrict__ mask, float* __restrict__ logit_out) {
    __shared__ char xs[64 * 512];        // 64 rows x 256 bf16, XOR-swizzled
    __shared__ float attp[4][64];

    const int tid = threadIdx.x;
    const int lane = tid & 63, w = tid >> 6;
    const size_t rowbase = (size_t)blockIdx.x * 64;
    const int b = (int)(rowbase >> 13);

    // ---- stage x tile into LDS (bf16, swizzled) ----
    if (MODE == 1) {
        const char* src = (const char*)xbf_in + rowbase * 512;
#pragma unroll
        for (int it = 0; it < 8; ++it) {
            int L = (it * 256 + tid) * 16;
            bf16x8 v = *(const bf16x8*)(src + L);
            int row = L >> 9, kb = L & 511;
            *(bf16x8*)(xs + row * 512 + (kb ^ ((row & 7) << 4))) = v;
        }
    } else {
        const float* src = x + rowbase * 256;
#pragma unroll
        for (int it = 0; it < 8; ++it) {
            int L = (it * 256 + tid) * 16;   // byte offset within bf16 tile
            int e = L >> 1;                  // f32 element offset (8 floats)
            float4 f0 = *(const float4*)(src + e);
            float4 f1 = *(const float4*)(src + e + 4);
            bf16x8 v;
            v[0] = (__bf16)f0.x; v[1] = (__bf16)f0.y; v[2] = (__bf16)f0.z; v[3] = (__bf16)f0.w;
            v[4] = (__bf16)f1.x; v[5] = (__bf16)f1.y; v[6] = (__bf16)f1.z; v[7] = (__bf16)f1.w;
            int row = L >> 9, kb = L & 511;
            *(bf16x8*)(xs + row * 512 + (kb ^ ((row & 7) << 4))) = v;
            if (MODE == 0)
                *(bf16x8*)((char*)xbf_out + rowbase * 512 + L) = v;
        }
    }

    // epilogue operands: issue early so latency hides under MFMA loop
    const int l15 = lane & 15, lg = lane >> 4;
    float w2v[4], swsv[4];
#pragma unroll
    for (int fn = 0; fn < 4; ++fn) {
        int h = w * 64 + fn * 16 + l15;
        w2v[fn] = w2[h];
        swsv[fn] = sws[b * 256 + h];
    }

    __syncthreads();

    // ---- MFMA: acc[fm][fn] = x_tile(64xK) · Wi^T slice (wave w covers cols w*64..+64) ----
    f32x4 acc[4][4] = {};
    const char* wib = (const char*)wi + (size_t)(w * 64 + l15) * 512 + lg * 16;
    bf16x8 bnext[4];
#pragma unroll
    for (int fn = 0; fn < 4; ++fn)
        bnext[fn] = *(const bf16x8*)(wib + fn * 8192);
#pragma unroll
    for (int kk = 0; kk < 8; ++kk) {
        bf16x8 bcur[4];
#pragma unroll
        for (int fn = 0; fn < 4; ++fn) bcur[fn] = bnext[fn];
        if (kk < 7) {
#pragma unroll
            for (int fn = 0; fn < 4; ++fn)
                bnext[fn] = *(const bf16x8*)(wib + fn * 8192 + (kk + 1) * 64);
        }
        bf16x8 afrag[4];
#pragma unroll
        for (int fm = 0; fm < 4; ++fm) {
            int row = fm * 16 + l15;
            int kb = kk * 64 + lg * 16;
            afrag[fm] = *(const bf16x8*)(xs + row * 512 + (kb ^ ((row & 7) << 4)));
        }
#pragma unroll
        for (int fm = 0; fm < 4; ++fm)
#pragma unroll
            for (int fn = 0; fn < 4; ++fn)
                acc[fm][fn] = __builtin_amdgcn_mfma_f32_16x16x32_bf16(
                    afrag[fm], bcur[fn], acc[fm][fn], 0, 0, 0);
    }

    // ---- epilogue: att = sum_h W2[h] * tanh(acc + sws[b][h]) ----
    const bool hi8 = (l15 & 8) != 0, hi4 = (l15 & 4) != 0;
    const int ridx = ((l15 & 8) >> 2) | ((l15 & 4) >> 2);
#pragma unroll
    for (int fm = 0; fm < 4; ++fm) {
        float part[4];
#pragma unroll
        for (int r = 0; r < 4; ++r) {
            float s = 0.f;
#pragma unroll
            for (int fn = 0; fn < 4; ++fn) {
                float hv = acc[fm][fn][r] + swsv[fn];
                s += w2v[fn] * fast_tanh(hv);
            }
            part[r] = s;
        }
        // distributed butterfly reduce over the 16 l15 lanes
        float s0 = hi8 ? part[0] : part[2];
        float s1 = hi8 ? part[1] : part[3];
        float r0 = __shfl_xor(s0, 8, 64);
        float r1 = __shfl_xor(s1, 8, 64);
        float a0 = (hi8 ? part[2] : part[0]) + r0;
        float a1 = (hi8 ? part[3] : part[1]) + r1;
        float s2 = hi4 ? a0 : a1;
        float r2 = __shfl_xor(s2, 4, 64);
        float bsum = (hi4 ? a1 : a0) + r2;
        bsum += __shfl_xor(bsum, 2, 64);
        bsum += __shfl_xor(bsum, 1, 64);
        if ((l15 & 3) == 0) attp[w][fm * 16 + lg * 4 + ridx] = bsum;
    }
    __syncthreads();
    if (tid < 64) {
        float att = attp[0][tid] + attp[1][tid] + attp[2][tid] + attp[3][tid];
        float mv = mask[rowbase + tid];
        logit_out[rowbase + tid] = att - NEGC * (1.f - mv);
    }
}

// ---------------------------------------------------------------------------
// per-chunk softmax stats over 1024 logits: stat[bc] = {max, sum exp(l - max)}
__global__ __launch_bounds__(256) void chunkstat_kernel(const float* __restrict__ logit,
                                                        float2* __restrict__ stat) {
    __shared__ float redm[4], reds[4];
    int bc = blockIdx.x, tid = threadIdx.x;
    const float* lp = logit + (size_t)bc * 1024;
    float4 v = *(const float4*)(lp + tid * 4);
    float m = fmaxf(fmaxf(v.x, v.y), fmaxf(v.z, v.w));
#pragma unroll
    for (int o = 1; o < 64; o <<= 1) m = fmaxf(m, __shfl_xor(m, o, 64));
    if ((tid & 63) == 0) redm[tid >> 6] = m;
    __syncthreads();
    m = fmaxf(fmaxf(redm[0], redm[1]), fmaxf(redm[2], redm[3]));
    float s = __expf(v.x - m) + __expf(v.y - m) + __expf(v.z - m) + __expf(v.w - m);
#pragma unroll
    for (int o = 1; o < 64; o <<= 1) s += __shfl_xor(s, o, 64);
    if ((tid & 63) == 0) reds[tid >> 6] = s;
    __syncthreads();
    if (tid == 0) {
        float2 st;
        st.x = m;
        st.y = reds[0] + reds[1] + reds[2] + reds[3];
        stat[bc] = st;
    }
}

// ---------------------------------------------------------------------------
// out_part[b][c][i] = sum_{t in 256-chunk c} p[b,t]*x[b,t,i], p online from stats.
// 1024 blocks (b,c). stats are per-1024-token chunk (8/batch).
template <int MODE>  // 0: bf16 x cache, 2: f32 x
__global__ __launch_bounds__(256) void outpart_kernel(
    const float* __restrict__ logit, const float2* __restrict__ stat,
    const float* __restrict__ xf, const __bf16* __restrict__ xbf,
    float* __restrict__ out_part) {
    int b = blockIdx.x >> 5, c = blockIdx.x & 31;
    int tid = threadIdx.x;
    int ig = tid & 31, tg = tid >> 5;
    __shared__ float pl[256];
    __shared__ float sacc[8][264];
    float m = -3.4e38f;
#pragma unroll
    for (int cc = 0; cc < 8; ++cc) m = fmaxf(m, stat[b * 8 + cc].x);
    float ssum = 0.f;
#pragma unroll
    for (int cc = 0; cc < 8; ++cc) {
        float2 st = stat[b * 8 + cc];
        ssum += st.y * __expf(st.x - m);
    }
    float invs = 1.f / ssum;
    const size_t tbase = (size_t)b * TT + (size_t)c * 256;
    pl[tid] = __expf(logit[tbase + tid] - m) * invs;
    __syncthreads();
    float a[8] = {};
    if (MODE == 0) {
        const __bf16* xp = xbf + tbase * 256 + ig * 8;
        for (int t = tg; t < 256; t += 8) {
            float pv = pl[t];
            bf16x8 v = *(const bf16x8*)(xp + (size_t)t * 256);
#pragma unroll
            for (int j = 0; j < 8; ++j) a[j] += pv * (float)v[j];
        }
    } else {
        const float* xp = xf + tbase * 256 + ig * 8;
        for (int t = tg; t < 256; t += 8) {
            float pv = pl[t];
            float4 f0 = *(const float4*)(xp + (size_t)t * 256);
            float4 f1 = *(const float4*)(xp + (size_t)t * 256 + 4);
            a[0] += pv * f0.x; a[1] += pv * f0.y; a[2] += pv * f0.z; a[3] += pv * f0.w;
            a[4] += pv * f1.x; a[5] += pv * f1.y; a[6] += pv * f1.z; a[7] += pv * f1.w;
        }
    }
#pragma unroll
    for (int j = 0; j < 8; ++j) sacc[tg][ig * 8 + j] = a[j];
    __syncthreads();
    float s = 0.f;
#pragma unroll
    for (int j = 0; j < 8; ++j) s += sacc[j][tid];
    out_part[(size_t)(b * 32 + c) * 256 + tid] = s;
}

// out_sum[b][i] = sum_c out_part[b][c][i]
__global__ __launch_bounds__(256) void outsum_kernel(const float* __restrict__ out_part,
                                                     float* __restrict__ out_sum) {
    int b = blockIdx.x, i = threadIdx.x;
    float s = 0.f;
#pragma unroll
    for (int c = 0; c < 32; ++c) s += out_part[(size_t)(b * 32 + c) * 256 + i];
    out_sum[b * 256 + i] = s;
}

// ---------------------------------------------------------------------------
// GRU gemm: gi[k][b] = b_ih[k] + sum_i w_ih[k][i]*out[b][i]; gh analog. 48 blocks.
__global__ __launch_bounds__(256) void gru_gemm_kernel(
    const float* __restrict__ out_sum, const float* __restrict__ init,
    const float* __restrict__ w_ih, const float* __restrict__ w_hh,
    const float* __restrict__ b_ih, const float* __restrict__ b_hh,
    float* __restrict__ gi, float* __restrict__ gh) {
    __shared__ float outv[32 * 257];
    __shared__ float initv[32 * 257];
    int tid = threadIdx.x;
    for (int e = tid; e < 8192; e += 256) {
        int b = e >> 8, i = e & 255;
        outv[b * 257 + i] = out_sum[b * 256 + i];
        initv[b * 257 + i] = init[b * 256 + i];
    }
    __syncthreads();
    int kl = tid >> 4, bg = tid & 15;
    int k = blockIdx.x * 16 + kl;
    const float* wir = w_ih + (size_t)k * 256;
    const float* whr = w_hh + (size_t)k * 256;
    float gia0 = b_ih[k], gia1 = gia0;
    float gha0 = b_hh[k], gha1 = gha0;
#pragma unroll 4
    for (int i = 0; i < 256; ++i) {
        float wiv = wir[i], whv = whr[i];
        gia0 += wiv * outv[(bg * 2 + 0) * 257 + i];
        gia1 += wiv * outv[(bg * 2 + 1) * 257 + i];
        gha0 += whv * initv[(bg * 2 + 0) * 257 + i];
        gha1 += whv * initv[(bg * 2 + 1) * 257 + i];
    }
    gi[k * 32 + bg * 2 + 0] = gia0;
    gi[k * 32 + bg * 2 + 1] = gia1;
    gh[k * 32 + bg * 2 + 0] = gha0;
    gh[k * 32 + bg * 2 + 1] = gha1;
}

// GRU pointwise
__global__ __launch_bounds__(256) void gru_point_kernel(
    const float* __restrict__ gi, const float* __restrict__ gh,
    const float* __restrict__ init, float* __restrict__ state) {
    int b = blockIdx.x, s = threadIdx.x;
    float gir = gi[s * 32 + b], giz = gi[(256 + s) * 32 + b], gin = gi[(512 + s) * 32 + b];
    float ghr = gh[s * 32 + b], ghz = gh[(256 + s) * 32 + b], ghn = gh[(512 + s) * 32 + b];
    float r = fast_sigmoid(gir + ghr);
    float z = fast_sigmoid(giz + ghz);
    float n = fast_tanh(gin + r * ghn);
    float h0 = init[b * 256 + s];
    state[b * 256 + s] = (1.f - z) * n + z * h0;
}

// ---------------------------------------------------------------------------
extern "C" void kernel_launch(void* const* d_in, const int* in_sizes, int n_in,
                              void* d_out, int out_size, void* d_ws, size_t ws_size,
                              hipStream_t stream) {
    const float* x = (const float*)d_in[0];
    const float* init = (const float*)d_in[1];
    const float* mask = (const float*)d_in[2];
    const float* W1 = (const float*)d_in[3];
    const float* W2 = (const float*)d_in[4];
    const float* w_ih = (const float*)d_in[5];
    const float* w_hh = (const float*)d_in[6];
    const float* b_ih = (const float*)d_in[7];
    const float* b_hh = (const float*)d_in[8];
    float* out = (float*)d_out;

    char* ws = (char*)d_ws;
    size_t off = 0;
    auto alloc = [&](size_t sz) {
        char* p = ws + off;
        off += (sz + 255) & ~(size_t)255;
        return p;
    };
    __bf16* wi = (__bf16*)alloc((size_t)HH * II * 2);
    float* sws1 = (float*)alloc(BB * 256 * 4);
    float* sws2 = (float*)alloc(BB * 256 * 4);
    float* out_part = (float*)alloc((size_t)BB * 32 * 256 * 4);
    float* out_sum = (float*)alloc(BB * 256 * 4);
    float2* stat = (float2*)alloc(BB * 8 * 8);
    float* gi_buf = (float*)alloc(768 * 32 * 4);
    float* gh_buf = (float*)alloc(768 * 32 * 4);
    float* state_buf = (float*)alloc(BB * 256 * 4);
    __bf16* xbf = (__bf16*)alloc((size_t)BB * TT * II * 2);
    const bool big = (off <= ws_size);
    (void)in_sizes; (void)n_in; (void)out_size;

    prep_kernel<<<272, 256, 0, stream>>>(W1, init, wi, sws1);

    const int ntiles = BB * TT / 64;  // 4096
    if (big)
        att_kernel<0><<<ntiles, 256, 0, stream>>>(x, nullptr, xbf, wi, W2, sws1, mask, out);
    else
        att_kernel<2><<<ntiles, 256, 0, stream>>>(x, nullptr, nullptr, wi, W2, sws1, mask, out);

    chunkstat_kernel<<<256, 256, 0, stream>>>(out, stat);

    if (big)
        outpart_kernel<0><<<1024, 256, 0, stream>>>(out, stat, nullptr, xbf, out_part);
    else
        outpart_kernel<2><<<1024, 256, 0, stream>>>(out, stat, x, nullptr, out_part);

    outsum_kernel<<<32, 256, 0, stream>>>(out_part, out_sum);
    gru_gemm_kernel<<<48, 256, 0, stream>>>(out_sum, init, w_ih, w_hh, b_ih, b_hh,
                                            gi_buf, gh_buf);
    gru_point_kernel<<<32, 256, 0, stream>>>(gi_buf, gh_buf, init, state_buf);
    sws_slice_kernel<<<16, 256, 0, stream>>>(state_buf, W1, sws2);

    if (big)
        att_kernel<1><<<ntiles, 256, 0, stream>>>(nullptr, xbf, nullptr, wi, W2, sws2, mask,
                                                  out + (size_t)BB * TT);
    else
        att_kernel<2><<<ntiles, 256, 0, stream>>>(x, nullptr, nullptr, wi, W2, sws2, mask,
                                                  out + (size_t)BB * TT);
}

// Round 4
// 557.141 us; speedup vs baseline: 1.2499x; 1.0141x over previous
//
#include <hip/hip_runtime.h>
#include <hip/hip_bf16.h>
#include <stdint.h>

#define BB 32
#define TT 8192
#define II 256
#define SS 256
#define HH 256
#define NEGC 1e30f

typedef __bf16 bf16x8 __attribute__((ext_vector_type(8)));
typedef __bf16 bf16x4 __attribute__((ext_vector_type(4)));
typedef float f32x4 __attribute__((ext_vector_type(4)));
typedef float f32x2 __attribute__((ext_vector_type(2)));

__device__ __forceinline__ float fast_tanh(float x) {
    float e = __expf(2.f * x);
    return 1.f - 2.f * __builtin_amdgcn_rcpf(e + 1.f);
}
__device__ __forceinline__ float fast_sigmoid(float x) {
    return __builtin_amdgcn_rcpf(1.f + __expf(-x));
}

// ---------------------------------------------------------------------------
// Fused prep: blocks 0..255 convert Wi (= W1[:, S:]) to bf16 [H][I];
// blocks 256..271 compute sws1[b][h] = sum_s init[b][s]*W1[h][s].
__global__ __launch_bounds__(256) void prep_kernel(const float* __restrict__ W1,
                                                   const float* __restrict__ init,
                                                   __bf16* __restrict__ wi,
                                                   float* __restrict__ sws) {
    __shared__ float sv[32 * 257];
    int tid = threadIdx.x;
    if (blockIdx.x < 256) {
        int idx = blockIdx.x * 256 + tid;
        int h = idx >> 8, k = idx & 255;
        wi[idx] = (__bf16)W1[h * 512 + 256 + k];
        return;
    }
    for (int e = tid; e < 8192; e += 256) {
        int b = e >> 8, s = e & 255;
        sv[b * 257 + s] = init[b * 256 + s];
    }
    __syncthreads();
    int hl = tid >> 4, bg = tid & 15;
    int h = (blockIdx.x - 256) * 16 + hl;
    const float* w1r = W1 + (size_t)h * 512;
    float a0 = 0.f, a1 = 0.f;
#pragma unroll 4
    for (int s = 0; s < 256; ++s) {
        float w = w1r[s];
        a0 += w * sv[(bg * 2 + 0) * 257 + s];
        a1 += w * sv[(bg * 2 + 1) * 257 + s];
    }
    sws[(bg * 2 + 0) * 256 + h] = a0;
    sws[(bg * 2 + 1) * 256 + h] = a1;
}

// ---------------------------------------------------------------------------
// sws[b][h] = sum_s state[b][s] * W1[h][s]  — 16 blocks
__global__ __launch_bounds__(256) void sws_slice_kernel(const float* __restrict__ state,
                                                        const float* __restrict__ W1,
                                                        float* __restrict__ sws) {
    __shared__ float sv[32 * 257];
    int tid = threadIdx.x;
    for (int e = tid; e < 8192; e += 256) {
        int b = e >> 8, s = e & 255;
        sv[b * 257 + s] = state[b * 256 + s];
    }
    __syncthreads();
    int hl = tid >> 4, bg = tid & 15;
    int h = blockIdx.x * 16 + hl;
    const float* w1r = W1 + (size_t)h * 512;
    float a0 = 0.f, a1 = 0.f;
#pragma unroll 4
    for (int s = 0; s < 256; ++s) {
        float w = w1r[s];
        a0 += w * sv[(bg * 2 + 0) * 257 + s];
        a1 += w * sv[(bg * 2 + 1) * 257 + s];
    }
    sws[(bg * 2 + 0) * 256 + h] = a0;
    sws[(bg * 2 + 1) * 256 + h] = a1;
}

// ---------------------------------------------------------------------------
// att1: logit[row] = sum_h W2[h]*tanh( xWi[row,h] + sws[b][h] ) - 1e30*(1-mask)
// MODE 0: also write xwi cache (fragment-permuted bf16), xfp8 cache, tilestat.
// MODE 2: fallback, no caches (tilestat only).
template <int MODE>
__global__ __launch_bounds__(256, 3) void att1_kernel(
    const float* __restrict__ x, const __bf16* __restrict__ wi,
    const float* __restrict__ w2, const float* __restrict__ sws,
    const float* __restrict__ mask, float* __restrict__ logit_out,
    __bf16* __restrict__ xwi, unsigned char* __restrict__ xfp8,
    float2* __restrict__ tstat) {
    __shared__ char xs[64 * 512];        // 64 rows x 256 bf16, XOR-swizzled
    __shared__ float attp[4][64];

    const int tid = threadIdx.x;
    const int lane = tid & 63, w = tid >> 6;
    const size_t rowbase = (size_t)blockIdx.x * 64;
    const int b = (int)(rowbase >> 13);

    // ---- stage x tile into LDS (bf16, swizzled); MODE 0 also emits fp8 cache ----
    {
        const float* src = x + rowbase * 256;
#pragma unroll
        for (int it = 0; it < 8; ++it) {
            int L = (it * 256 + tid) * 16;   // byte offset within bf16 tile
            int e = L >> 1;                  // f32 element offset (8 floats)
            float4 f0 = *(const float4*)(src + e);
            float4 f1 = *(const float4*)(src + e + 4);
            bf16x8 v;
            v[0] = (__bf16)f0.x; v[1] = (__bf16)f0.y; v[2] = (__bf16)f0.z; v[3] = (__bf16)f0.w;
            v[4] = (__bf16)f1.x; v[5] = (__bf16)f1.y; v[6] = (__bf16)f1.z; v[7] = (__bf16)f1.w;
            int row = L >> 9, kb = L & 511;
            *(bf16x8*)(xs + row * 512 + (kb ^ ((row & 7) << 4))) = v;
            if (MODE == 0) {
                unsigned int lo = __builtin_amdgcn_cvt_pk_fp8_f32(f0.x, f0.y, 0u, false);
                lo = __builtin_amdgcn_cvt_pk_fp8_f32(f0.z, f0.w, lo, true);
                unsigned int hi = __builtin_amdgcn_cvt_pk_fp8_f32(f1.x, f1.y, 0u, false);
                hi = __builtin_amdgcn_cvt_pk_fp8_f32(f1.z, f1.w, hi, true);
                uint2 pk; pk.x = lo; pk.y = hi;
                *(uint2*)(xfp8 + rowbase * 256 + e) = pk;
            }
        }
    }

    // epilogue operands: issue early so latency hides under MFMA loop
    const int l15 = lane & 15, lg = lane >> 4;
    float w2v[4], swsv[4];
#pragma unroll
    for (int fn = 0; fn < 4; ++fn) {
        int h = w * 64 + fn * 16 + l15;
        w2v[fn] = w2[h];
        swsv[fn] = sws[b * 256 + h];
    }

    __syncthreads();

    // ---- MFMA: acc[fm][fn] = x_tile(64xK) · Wi^T slice (wave w covers cols w*64..+64) ----
    f32x4 acc[4][4] = {};
    const char* wib = (const char*)wi + (size_t)(w * 64 + l15) * 512 + lg * 16;
    bf16x8 bnext[4];
#pragma unroll
    for (int fn = 0; fn < 4; ++fn)
        bnext[fn] = *(const bf16x8*)(wib + fn * 8192);
#pragma unroll
    for (int kk = 0; kk < 8; ++kk) {
        bf16x8 bcur[4];
#pragma unroll
        for (int fn = 0; fn < 4; ++fn) bcur[fn] = bnext[fn];
        if (kk < 7) {
#pragma unroll
            for (int fn = 0; fn < 4; ++fn)
                bnext[fn] = *(const bf16x8*)(wib + fn * 8192 + (kk + 1) * 64);
        }
        bf16x8 afrag[4];
#pragma unroll
        for (int fm = 0; fm < 4; ++fm) {
            int row = fm * 16 + l15;
            int kb = kk * 64 + lg * 16;
            afrag[fm] = *(const bf16x8*)(xs + row * 512 + (kb ^ ((row & 7) << 4)));
        }
#pragma unroll
        for (int fm = 0; fm < 4; ++fm)
#pragma unroll
            for (int fn = 0; fn < 4; ++fn)
                acc[fm][fn] = __builtin_amdgcn_mfma_f32_16x16x32_bf16(
                    afrag[fm], bcur[fn], acc[fm][fn], 0, 0, 0);
    }

    // ---- MODE 0: store xwi cache in fragment-permuted layout (coalesced) ----
    // chunk = ((tile*16 + w*4 + fm)*128 + lane*2 + half) of 16B; elem order fn*4+r.
    if (MODE == 0) {
#pragma unroll
        for (int fm = 0; fm < 4; ++fm) {
            bf16x8 p0, p1;
#pragma unroll
            for (int r = 0; r < 4; ++r) {
                p0[0 * 4 + r] = (__bf16)acc[fm][0][r];
                p0[1 * 4 + r] = (__bf16)acc[fm][1][r];
                p1[0 * 4 + r] = (__bf16)acc[fm][2][r];
                p1[1 * 4 + r] = (__bf16)acc[fm][3][r];
            }
            size_t base = (((size_t)blockIdx.x * 16 + w * 4 + fm) * 128 + lane * 2) * 8;
            *(bf16x8*)(xwi + base) = p0;
            *(bf16x8*)(xwi + base + 8) = p1;
        }
    }

    // ---- epilogue: att = sum_h W2[h] * tanh(acc + sws[b][h]) ----
    const bool hi8 = (l15 & 8) != 0, hi4 = (l15 & 4) != 0;
    const int ridx = ((l15 & 8) >> 2) | ((l15 & 4) >> 2);
#pragma unroll
    for (int fm = 0; fm < 4; ++fm) {
        float part[4];
#pragma unroll
        for (int r = 0; r < 4; ++r) {
            float s = 0.f;
#pragma unroll
            for (int fn = 0; fn < 4; ++fn) {
                float hv = acc[fm][fn][r] + swsv[fn];
                s += w2v[fn] * fast_tanh(hv);
            }
            part[r] = s;
        }
        float s0 = hi8 ? part[0] : part[2];
        float s1 = hi8 ? part[1] : part[3];
        float r0 = __shfl_xor(s0, 8, 64);
        float r1 = __shfl_xor(s1, 8, 64);
        float a0 = (hi8 ? part[2] : part[0]) + r0;
        float a1 = (hi8 ? part[3] : part[1]) + r1;
        float s2 = hi4 ? a0 : a1;
        float r2 = __shfl_xor(s2, 4, 64);
        float bsum = (hi4 ? a1 : a0) + r2;
        bsum += __shfl_xor(bsum, 2, 64);
        bsum += __shfl_xor(bsum, 1, 64);
        if ((l15 & 3) == 0) attp[w][fm * 16 + lg * 4 + ridx] = bsum;
    }
    __syncthreads();
    if (tid < 64) {
        float att = attp[0][tid] + attp[1][tid] + attp[2][tid] + attp[3][tid];
        float mv = mask[rowbase + tid];
        float lgt = att - NEGC * (1.f - mv);
        logit_out[rowbase + tid] = lgt;
        // per-tile softmax stats (wave 0 only): {max, sum exp(l - max)}
        float m = lgt;
#pragma unroll
        for (int o = 1; o < 64; o <<= 1) m = fmaxf(m, __shfl_xor(m, o, 64));
        float e = __expf(lgt - m);
#pragma unroll
        for (int o = 1; o < 64; o <<= 1) e += __shfl_xor(e, o, 64);
        if (tid == 0) {
            float2 st; st.x = m; st.y = e;
            tstat[blockIdx.x] = st;
        }
    }
}

// ---------------------------------------------------------------------------
// att2: streaming — logit2[row] = sum_h W2[h]*tanh(xwi[row,h]+sws2[b][h]) - mask term.
// Reads the fragment-permuted xwi cache with the same (w,fm,lane,fn,r) mapping.
__global__ __launch_bounds__(256) void att2_kernel(
    const __bf16* __restrict__ xwi, const float* __restrict__ w2,
    const float* __restrict__ sws, const float* __restrict__ mask,
    float* __restrict__ logit_out) {
    __shared__ float attp[4][64];
    const int tid = threadIdx.x;
    const int lane = tid & 63, w = tid >> 6;
    const size_t rowbase = (size_t)blockIdx.x * 64;
    const int b = (int)(rowbase >> 13);
    const int l15 = lane & 15, lg = lane >> 4;
    float w2v[4], swsv[4];
#pragma unroll
    for (int fn = 0; fn < 4; ++fn) {
        int h = w * 64 + fn * 16 + l15;
        w2v[fn] = w2[h];
        swsv[fn] = sws[b * 256 + h];
    }
    const bool hi8 = (l15 & 8) != 0, hi4 = (l15 & 4) != 0;
    const int ridx = ((l15 & 8) >> 2) | ((l15 & 4) >> 2);
#pragma unroll
    for (int fm = 0; fm < 4; ++fm) {
        size_t base = (((size_t)blockIdx.x * 16 + w * 4 + fm) * 128 + lane * 2) * 8;
        bf16x8 p0 = *(const bf16x8*)(xwi + base);
        bf16x8 p1 = *(const bf16x8*)(xwi + base + 8);
        float part[4];
#pragma unroll
        for (int r = 0; r < 4; ++r) {
            float s = 0.f;
            s += w2v[0] * fast_tanh((float)p0[0 * 4 + r] + swsv[0]);
            s += w2v[1] * fast_tanh((float)p0[1 * 4 + r] + swsv[1]);
            s += w2v[2] * fast_tanh((float)p1[0 * 4 + r] + swsv[2]);
            s += w2v[3] * fast_tanh((float)p1[1 * 4 + r] + swsv[3]);
            part[r] = s;
        }
        float s0 = hi8 ? part[0] : part[2];
        float s1 = hi8 ? part[1] : part[3];
        float r0 = __shfl_xor(s0, 8, 64);
        float r1 = __shfl_xor(s1, 8, 64);
        float a0 = (hi8 ? part[2] : part[0]) + r0;
        float a1 = (hi8 ? part[3] : part[1]) + r1;
        float s2 = hi4 ? a0 : a1;
        float r2 = __shfl_xor(s2, 4, 64);
        float bsum = (hi4 ? a1 : a0) + r2;
        bsum += __shfl_xor(bsum, 2, 64);
        bsum += __shfl_xor(bsum, 1, 64);
        if ((l15 & 3) == 0) attp[w][fm * 16 + lg * 4 + ridx] = bsum;
    }
    __syncthreads();
    if (tid < 64) {
        float att = attp[0][tid] + attp[1][tid] + attp[2][tid] + attp[3][tid];
        float mv = mask[rowbase + tid];
        logit_out[rowbase + tid] = att - NEGC * (1.f - mv);
    }
}

// ---------------------------------------------------------------------------
// out_part[b][c][i] = sum_{t in 128-chunk c} p[b,t]*x[b,t,i]; p online from
// per-tile stats (128 tiles/batch). 2048 blocks (b, c).
template <int MODE>  // 0: fp8 x cache, 2: f32 x
__global__ __launch_bounds__(256) void outpart_kernel(
    const float* __restrict__ logit, const float2* __restrict__ tstat,
    const float* __restrict__ xf, const unsigned char* __restrict__ xfp8,
    float* __restrict__ out_part) {
    int b = blockIdx.x >> 6, c = blockIdx.x & 63;
    int tid = threadIdx.x;
    int ig = tid & 31, tg = tid >> 5;
    __shared__ float pl[128];
    __shared__ float sacc[8][264];
    float M = -3.4e38f;
#pragma unroll 8
    for (int i = 0; i < 128; ++i) M = fmaxf(M, tstat[b * 128 + i].x);
    float S = 0.f;
#pragma unroll 8
    for (int i = 0; i < 128; ++i) {
        float2 st = tstat[b * 128 + i];
        S += st.y * __expf(st.x - M);
    }
    float invs = 1.f / S;
    const size_t tbase = (size_t)b * TT + (size_t)c * 128;
    if (tid < 128) pl[tid] = __expf(logit[tbase + tid] - M) * invs;
    __syncthreads();
    float a[8] = {};
    if (MODE == 0) {
        const unsigned char* xp = xfp8 + tbase * 256 + ig * 8;
        for (int t = tg; t < 128; t += 8) {
            float pv = pl[t];
            uint2 v = *(const uint2*)(xp + (size_t)t * 256);
            f32x2 d0 = __builtin_amdgcn_cvt_pk_f32_fp8(v.x, false);
            f32x2 d1 = __builtin_amdgcn_cvt_pk_f32_fp8(v.x, true);
            f32x2 d2 = __builtin_amdgcn_cvt_pk_f32_fp8(v.y, false);
            f32x2 d3 = __builtin_amdgcn_cvt_pk_f32_fp8(v.y, true);
            a[0] += pv * d0[0]; a[1] += pv * d0[1];
            a[2] += pv * d1[0]; a[3] += pv * d1[1];
            a[4] += pv * d2[0]; a[5] += pv * d2[1];
            a[6] += pv * d3[0]; a[7] += pv * d3[1];
        }
    } else {
        const float* xp = xf + tbase * 256 + ig * 8;
        for (int t = tg; t < 128; t += 8) {
            float pv = pl[t];
            float4 f0 = *(const float4*)(xp + (size_t)t * 256);
            float4 f1 = *(const float4*)(xp + (size_t)t * 256 + 4);
            a[0] += pv * f0.x; a[1] += pv * f0.y; a[2] += pv * f0.z; a[3] += pv * f0.w;
            a[4] += pv * f1.x; a[5] += pv * f1.y; a[6] += pv * f1.z; a[7] += pv * f1.w;
        }
    }
#pragma unroll
    for (int j = 0; j < 8; ++j) sacc[tg][ig * 8 + j] = a[j];
    __syncthreads();
    float s = 0.f;
#pragma unroll
    for (int j = 0; j < 8; ++j) s += sacc[j][tid];
    out_part[(size_t)(b * 64 + c) * 256 + tid] = s;
}

// out_sum[b][i] = sum_c out_part[b][c][i]
__global__ __launch_bounds__(256) void outsum_kernel(const float* __restrict__ out_part,
                                                     float* __restrict__ out_sum) {
    int b = blockIdx.x, i = threadIdx.x;
    float s = 0.f;
#pragma unroll
    for (int c = 0; c < 64; ++c) s += out_part[(size_t)(b * 64 + c) * 256 + i];
    out_sum[b * 256 + i] = s;
}

// ---------------------------------------------------------------------------
// GRU gemm: gi[k][b] = b_ih[k] + sum_i w_ih[k][i]*out[b][i]; gh analog. 48 blocks.
__global__ __launch_bounds__(256) void gru_gemm_kernel(
    const float* __restrict__ out_sum, const float* __restrict__ init,
    const float* __restrict__ w_ih, const float* __restrict__ w_hh,
    const float* __restrict__ b_ih, const float* __restrict__ b_hh,
    float* __restrict__ gi, float* __restrict__ gh) {
    __shared__ float outv[32 * 257];
    __shared__ float initv[32 * 257];
    int tid = threadIdx.x;
    for (int e = tid; e < 8192; e += 256) {
        int b = e >> 8, i = e & 255;
        outv[b * 257 + i] = out_sum[b * 256 + i];
        initv[b * 257 + i] = init[b * 256 + i];
    }
    __syncthreads();
    int kl = tid >> 4, bg = tid & 15;
    int k = blockIdx.x * 16 + kl;
    const float* wir = w_ih + (size_t)k * 256;
    const float* whr = w_hh + (size_t)k * 256;
    float gia0 = b_ih[k], gia1 = gia0;
    float gha0 = b_hh[k], gha1 = gha0;
#pragma unroll 4
    for (int i = 0; i < 256; ++i) {
        float wiv = wir[i], whv = whr[i];
        gia0 += wiv * outv[(bg * 2 + 0) * 257 + i];
        gia1 += wiv * outv[(bg * 2 + 1) * 257 + i];
        gha0 += whv * initv[(bg * 2 + 0) * 257 + i];
        gha1 += whv * initv[(bg * 2 + 1) * 257 + i];
    }
    gi[k * 32 + bg * 2 + 0] = gia0;
    gi[k * 32 + bg * 2 + 1] = gia1;
    gh[k * 32 + bg * 2 + 0] = gha0;
    gh[k * 32 + bg * 2 + 1] = gha1;
}

// GRU pointwise
__global__ __launch_bounds__(256) void gru_point_kernel(
    const float* __restrict__ gi, const float* __restrict__ gh,
    const float* __restrict__ init, float* __restrict__ state) {
    int b = blockIdx.x, s = threadIdx.x;
    float gir = gi[s * 32 + b], giz = gi[(256 + s) * 32 + b], gin = gi[(512 + s) * 32 + b];
    float ghr = gh[s * 32 + b], ghz = gh[(256 + s) * 32 + b], ghn = gh[(512 + s) * 32 + b];
    float r = fast_sigmoid(gir + ghr);
    float z = fast_sigmoid(giz + ghz);
    float n = fast_tanh(gin + r * ghn);
    float h0 = init[b * 256 + s];
    state[b * 256 + s] = (1.f - z) * n + z * h0;
}

// ---------------------------------------------------------------------------
extern "C" void kernel_launch(void* const* d_in, const int* in_sizes, int n_in,
                              void* d_out, int out_size, void* d_ws, size_t ws_size,
                              hipStream_t stream) {
    const float* x = (const float*)d_in[0];
    const float* init = (const float*)d_in[1];
    const float* mask = (const float*)d_in[2];
    const float* W1 = (const float*)d_in[3];
    const float* W2 = (const float*)d_in[4];
    const float* w_ih = (const float*)d_in[5];
    const float* w_hh = (const float*)d_in[6];
    const float* b_ih = (const float*)d_in[7];
    const float* b_hh = (const float*)d_in[8];
    float* out = (float*)d_out;

    char* ws = (char*)d_ws;
    size_t off = 0;
    auto alloc = [&](size_t sz) {
        char* p = ws + off;
        off += (sz + 255) & ~(size_t)255;
        return p;
    };
    __bf16* wi = (__bf16*)alloc((size_t)HH * II * 2);
    float* sws1 = (float*)alloc(BB * 256 * 4);
    float* sws2 = (float*)alloc(BB * 256 * 4);
    float* out_part = (float*)alloc((size_t)BB * 64 * 256 * 4);
    float* out_sum = (float*)alloc(BB * 256 * 4);
    float2* tstat = (float2*)alloc(4096 * 8);
    float* gi_buf = (float*)alloc(768 * 32 * 4);
    float* gh_buf = (float*)alloc(768 * 32 * 4);
    float* state_buf = (float*)alloc(BB * 256 * 4);
    __bf16* xwi = (__bf16*)alloc((size_t)BB * TT * HH * 2);
    unsigned char* xfp8 = (unsigned char*)alloc((size_t)BB * TT * II);
    const bool big = (off <= ws_size);
    (void)in_sizes; (void)n_in; (void)out_size;

    prep_kernel<<<272, 256, 0, stream>>>(W1, init, wi, sws1);

    const int ntiles = BB * TT / 64;  // 4096
    if (big)
        att1_kernel<0><<<ntiles, 256, 0, stream>>>(x, wi, W2, sws1, mask, out,
                                                   xwi, xfp8, tstat);
    else
        att1_kernel<2><<<ntiles, 256, 0, stream>>>(x, wi, W2, sws1, mask, out,
                                                   nullptr, nullptr, tstat);

    if (big)
        outpart_kernel<0><<<2048, 256, 0, stream>>>(out, tstat, nullptr, xfp8, out_part);
    else
        outpart_kernel<2><<<2048, 256, 0, stream>>>(out, tstat, x, nullptr, out_part);

    outsum_kernel<<<32, 256, 0, stream>>>(out_part, out_sum);
    gru_gemm_kernel<<<48, 256, 0, stream>>>(out_sum, init, w_ih, w_hh, b_ih, b_hh,
                                            gi_buf, gh_buf);
    gru_point_kernel<<<32, 256, 0, stream>>>(gi_buf, gh_buf, init, state_buf);
    sws_slice_kernel<<<16, 256, 0, stream>>>(state_buf, W1, sws2);

    if (big)
        att2_kernel<<<ntiles, 256, 0, stream>>>(xwi, W2, sws2, mask,
                                                out + (size_t)BB * TT);
    else
        att1_kernel<2><<<ntiles, 256, 0, stream>>>(x, wi, W2, sws2, mask,
                                                   out + (size_t)BB * TT,
                                                   nullptr, nullptr, tstat);
}